// Round 9
// baseline (353.694 us; speedup 1.0000x reference)
//
#include <hip/hip_runtime.h>
#include <hip/hip_bf16.h>
#include <math.h>

#define DM 1024
#define SEQ 2048
#define DH 64
#define NH 16
#define DMLP 4096
#define BATCH 2
#define ROWS (BATCH*SEQ)   // 4096

typedef __attribute__((ext_vector_type(4))) float f32x4;
typedef __attribute__((ext_vector_type(8))) short bf16x8;

__device__ __forceinline__ void gl2lds16(const __hip_bfloat16* g, __hip_bfloat16* l) {
  __builtin_amdgcn_global_load_lds(
      (const __attribute__((address_space(1))) void*)g,
      (__attribute__((address_space(3))) void*)l, 16, 0, 0);
}

// ---------------------------------------------------------------------------
// bf16 GEMM: C[M,N] = A[M,K] * BT[N,K]^T.  TM x 128 tile, 256 thr, 16x16x32
// MFMA, double-buffered global_load_lds staging. All four GEMMs use this
// (R9: mlp1 moved off gemm256's 1-block/CU grid to (32,32) = 4 blocks/CU).
// QKV=1: N-blocks with n0 >= 2048 (the V section) write DIRECTLY to
// vt[(bh*64+e)*SEQ + s] (8B short4 per thread: 4 consecutive s) -- fuses
// the old transpose_v kernel into the epilogue; qkvb's V section is unused.
// SPLIT>1: blockIdx.z takes K/SPLIT chunk -> fp32 partials at z*zstride.
// XCD: blockIdx.x = M-tile, gridDim.x % 8 == 0.
// ---------------------------------------------------------------------------
template<int TM, int SPLIT, int OUT_BF16, int BIAS, int RELU, int QKV>
__global__ __launch_bounds__(256) void gemm_bt(
    const __hip_bfloat16* __restrict__ A,
    const __hip_bfloat16* __restrict__ BT,
    float* __restrict__ Cf,
    __hip_bfloat16* __restrict__ Cb,
    const float* __restrict__ bias,
    int M, int N, int K, long long zstride,
    __hip_bfloat16* __restrict__ vtout)
{
  constexpr int ASZ = TM*32;
  constexpr int MI  = (TM == 128) ? 4 : 2;
  __shared__ __align__(16) __hip_bfloat16 As[2*ASZ];
  __shared__ __align__(16) __hip_bfloat16 Bs[2*4096];
  const int t    = threadIdx.x;
  const int wave = t >> 6;
  const int lane = t & 63;
  const int col  = lane & 15;
  const int quad = lane >> 4;
  const int m0 = blockIdx.x * TM;     // M on x: XCD-local A reuse
  const int n0 = blockIdx.y * 128;
  const int wm = (wave >> 1) * (TM/2);
  const int wn = (wave & 1) * 64;

  const int Ks = K / SPLIT;
  const int kz = (SPLIT > 1) ? (int)blockIdx.z * Ks : 0;

  const int srow = t >> 2;
  const int scw  = ((t & 3) ^ ((srow >> 1) & 3)) * 8;
  const __hip_bfloat16* gA = A  + (size_t)(m0 + srow) * K + kz + scw;
  const __hip_bfloat16* gB = BT + (size_t)(n0 + srow) * K + kz + scw;
  const size_t rstep = (size_t)64 * K;

  const int scr = (quad ^ ((col >> 1) & 3)) * 8;

  f32x4 acc[MI][4] = {};

#define ISSUE(k0, buf) do {                                            \
    __hip_bfloat16* la = As + (buf)*ASZ  + wave*512;                   \
    __hip_bfloat16* lb = Bs + (buf)*4096 + wave*512;                   \
    gl2lds16(gA + (k0), la);                                           \
    if (TM == 128) gl2lds16(gA + rstep + (k0), la + 2048);             \
    gl2lds16(gB + (k0), lb);                                           \
    gl2lds16(gB + rstep + (k0), lb + 2048);                            \
  } while (0)

  ISSUE(0, 0);
  for (int k0 = 0; k0 < Ks; k0 += 32) {
    const int cur = (k0 >> 5) & 1;
    __syncthreads();                 // drains vmcnt(0): cur buffer ready
    if (k0 + 32 < Ks) ISSUE(k0 + 32, cur ^ 1);   // in flight during compute
    const __hip_bfloat16* Ab = As + cur*ASZ;
    const __hip_bfloat16* Bb = Bs + cur*4096;
    bf16x8 af[MI], bf[4];
    #pragma unroll
    for (int i = 0; i < MI; i++)
      af[i] = *(const bf16x8*)&Ab[(wm + i*16 + col)*32 + scr];
    #pragma unroll
    for (int j = 0; j < 4; j++)
      bf[j] = *(const bf16x8*)&Bb[(wn + j*16 + col)*32 + scr];
    #pragma unroll
    for (int i = 0; i < MI; i++)
      #pragma unroll
      for (int j = 0; j < 4; j++)
        acc[i][j] = __builtin_amdgcn_mfma_f32_16x16x32_bf16(af[i], bf[j], acc[i][j], 0, 0, 0);
  }
#undef ISSUE

  float* Cfz = (SPLIT > 1) ? (Cf + (size_t)blockIdx.z * zstride) : Cf;

  if (QKV && n0 >= 2048) {
    // V section: write transposed to vt[(bh*64+e)*SEQ + s].
    // Per (i,j): 4 r-values = 4 consecutive s -> one aligned 8B store.
    #pragma unroll
    for (int i = 0; i < MI; i++) {
      const int cm0 = m0 + wm + i*16 + quad*4;   // row of C (r adds 0..3)
      const int bb  = cm0 >> 11;                 // batch (SEQ=2048)
      const int s   = cm0 & 2047;                // seq pos (mult of 4)
      #pragma unroll
      for (int j = 0; j < 4; j++) {
        const int cn2 = n0 + wn + j*16 + col - 2048;  // 0..1023
        const int hh = cn2 >> 6, e = cn2 & 63;
        __hip_bfloat16 tmp[4];
        #pragma unroll
        for (int r = 0; r < 4; r++) tmp[r] = __float2bfloat16(acc[i][j][r]);
        *(short4*)&vtout[((size_t)(bb*16 + hh)*64 + e)*SEQ + s] = *(const short4*)tmp;
      }
    }
    return;
  }

  #pragma unroll
  for (int i = 0; i < MI; i++) {
    #pragma unroll
    for (int j = 0; j < 4; j++) {
      const int cn = n0 + wn + j*16 + col;
      float bv = 0.f;
      if (BIAS) bv = bias[cn];
      #pragma unroll
      for (int r = 0; r < 4; r++) {
        const int cm = m0 + wm + i*16 + quad*4 + r;   // C/D: col=lane&15, row=quad*4+reg
        float v = acc[i][j][r];
        if (BIAS) v += bv;
        if (RELU) v = fmaxf(v, 0.f);
        if (OUT_BF16) Cb[(size_t)cm * N + cn] = __float2bfloat16(v);
        else          Cfz[(size_t)cm * N + cn] = v;
      }
    }
  }
}

// ---------------------------------------------------------------------------
// Flash attention (R6/R8 proven version). R7 post-mortem: attn needs ~16
// waves/CU to hide LDS/global latency; 2-wave blocks collapsed all pipes.
// Grid (bh=32, y=16, z=2) = 1024 blocks of 256 thr = 4 blocks/CU (LDS 40KiB).
// Q in registers; K/V double-buffered global_load_lds w/ XOR swizzle;
// no-max softmax, deferred l-reduction.
// ---------------------------------------------------------------------------
__global__ __launch_bounds__(256) void attn_kernel(
    const __hip_bfloat16* __restrict__ qkv,
    const __hip_bfloat16* __restrict__ vt,
    __hip_bfloat16* __restrict__ aout)
{
  __shared__ __align__(16) __hip_bfloat16 Ks[2][64*64];
  __shared__ __align__(16) __hip_bfloat16 Vts[2][64*64];
  __shared__ __align__(16) __hip_bfloat16 Ps[4][16*64];

  const int bh = blockIdx.x, b = bh >> 4, h = bh & 15;
  const int t = threadIdx.x, wave = t >> 6, lane = t & 63;
  const int col = lane & 15, quad = lane >> 4;
  const float SC = 0.125f * 1.44269504f;   // 1/sqrt(dh) * log2(e)

  const int r0  = t >> 3;                 // row within 32-row half
  const int cs0 = (t & 7) ^ (r0 & 7);     // XOR-swizzled source chunk
  const __hip_bfloat16* kbase = qkv + (size_t)b*SEQ*3072 + 1024 + h*64;
  const __hip_bfloat16* vbase = vt + (size_t)bh*64*SEQ;

#define AISSUE(j0, buf) do {                                                      \
    gl2lds16(kbase + (size_t)((j0) + r0)*3072      + cs0*8, &Ks[buf][wave*512]);  \
    gl2lds16(kbase + (size_t)((j0) + 32 + r0)*3072 + cs0*8, &Ks[buf][2048 + wave*512]); \
    gl2lds16(vbase + (size_t)r0*SEQ        + (j0) + cs0*8,  &Vts[buf][wave*512]); \
    gl2lds16(vbase + (size_t)(32 + r0)*SEQ + (j0) + cs0*8,  &Vts[buf][2048 + wave*512]); \
  } while (0)

  const int tile = blockIdx.z ? (31 - (int)blockIdx.y) : (int)blockIdx.y;
  const int i0 = tile * 64;
  const int i0w = i0 + wave*16;

  bf16x8 aq[2];
  #pragma unroll
  for (int kk = 0; kk < 2; kk++)
    aq[kk] = *(const bf16x8*)&qkv[((size_t)(b*SEQ + i0w + col))*3072 + h*64 + kk*32 + quad*8];

  f32x4 O[4] = {};
  float lsum[4] = {0.f, 0.f, 0.f, 0.f};

  const int njt = tile + 1;
  AISSUE(0, 0);
  for (int jt = 0; jt < njt; jt++) {
    const int cur = jt & 1;
    const int j0 = jt * 64;
    __syncthreads();        // drains vmcnt(0): cur buffers ready
    if (jt + 1 < njt) AISSUE(j0 + 64, cur ^ 1);

    f32x4 S[4] = {};
    #pragma unroll
    for (int kk = 0; kk < 2; kk++) {
      const int sl = ((kk*4 + quad) ^ (col & 7)) * 8;
      #pragma unroll
      for (int jl = 0; jl < 4; jl++) {
        bf16x8 bk = *(const bf16x8*)&Ks[cur][(jl*16 + col)*64 + sl];
        S[jl] = __builtin_amdgcn_mfma_f32_16x16x32_bf16(aq[kk], bk, S[jl], 0, 0, 0);
      }
    }

    const bool diag = (jt == tile);
    #pragma unroll
    for (int r = 0; r < 4; r++) {
      const int row = quad*4 + r;
      const int ig = i0 + wave*16 + row;
      #pragma unroll
      for (int jl = 0; jl < 4; jl++) {
        float p = exp2f(S[jl][r] * SC);
        if (diag && (j0 + jl*16 + col > ig)) p = 0.f;
        lsum[r] += p;
        const int c = jl*2 + (col >> 3);
        Ps[wave][row*64 + (c ^ (row & 7))*8 + (col & 7)] = __float2bfloat16(p);
      }
    }

    #pragma unroll
    for (int kk = 0; kk < 2; kk++) {
      const int sl = ((kk*4 + quad) ^ (col & 7)) * 8;
      bf16x8 ap = *(const bf16x8*)&Ps[wave][col*64 + sl];
      #pragma unroll
      for (int et = 0; et < 4; et++) {
        bf16x8 bv = *(const bf16x8*)&Vts[cur][(et*16 + col)*64 + sl];
        O[et] = __builtin_amdgcn_mfma_f32_16x16x32_bf16(ap, bv, O[et], 0, 0, 0);
      }
    }
  }

  #pragma unroll
  for (int r = 0; r < 4; r++) {
    float s = lsum[r];
    s += __shfl_xor(s, 1);
    s += __shfl_xor(s, 2);
    s += __shfl_xor(s, 4);
    s += __shfl_xor(s, 8);
    const float inv = 1.f / s;
    const int m = b*SEQ + i0w + quad*4 + r;
    #pragma unroll
    for (int et = 0; et < 4; et++)
      aout[(size_t)m*DM + h*64 + et*16 + col] = __float2bfloat16(O[et][r] * inv);
  }
#undef AISSUE
}

// ---------------------------------------------------------------------------
// LayerNorm(y0 [+ y1 + y2 + y3] [+ bias])*g + b + residual -> fp32 out
// (+ opt bf16 copy).  y1..y3 nullable (split-K partial sums).
// ---------------------------------------------------------------------------
__global__ __launch_bounds__(256) void ln_res(
    const float* __restrict__ y0,
    const float* __restrict__ y1,
    const float* __restrict__ y2,
    const float* __restrict__ y3,
    const float* __restrict__ bias,
    const float* __restrict__ xres,
    float* __restrict__ xout,
    __hip_bfloat16* __restrict__ bout,
    const float* __restrict__ gamma,
    const float* __restrict__ beta)
{
  const int row = blockIdx.x;
  const int t = threadIdx.x;
  float4 v = ((const float4*)(y0 + (size_t)row*DM))[t];
  if (y1) {
    const float4 w = ((const float4*)(y1 + (size_t)row*DM))[t];
    v.x += w.x; v.y += w.y; v.z += w.z; v.w += w.w;
  }
  if (y2) {
    const float4 w = ((const float4*)(y2 + (size_t)row*DM))[t];
    v.x += w.x; v.y += w.y; v.z += w.z; v.w += w.w;
  }
  if (y3) {
    const float4 w = ((const float4*)(y3 + (size_t)row*DM))[t];
    v.x += w.x; v.y += w.y; v.z += w.z; v.w += w.w;
  }
  if (bias) {
    const float4 w = ((const float4*)bias)[t];
    v.x += w.x; v.y += w.y; v.z += w.z; v.w += w.w;
  }
  float s  = v.x + v.y + v.z + v.w;
  float sq = v.x*v.x + v.y*v.y + v.z*v.z + v.w*v.w;
  #pragma unroll
  for (int off = 32; off > 0; off >>= 1) {
    s  += __shfl_down(s, off);
    sq += __shfl_down(sq, off);
  }
  __shared__ float red[8];
  const int wave = t >> 6, lane = t & 63;
  if (lane == 0) { red[wave] = s; red[4 + wave] = sq; }
  __syncthreads();
  s  = red[0] + red[1] + red[2] + red[3];
  sq = red[4] + red[5] + red[6] + red[7];
  const float mu   = s * (1.f/DM);
  const float var  = sq * (1.f/DM) - mu*mu;
  const float rstd = rsqrtf(var + 1e-5f);
  const float4 g  = ((const float4*)gamma)[t];
  const float4 bt = ((const float4*)beta)[t];
  const float4 xr = ((const float4*)(xres + (size_t)row*DM))[t];
  float4 o;
  o.x = (v.x - mu)*rstd*g.x + bt.x + xr.x;
  o.y = (v.y - mu)*rstd*g.y + bt.y + xr.y;
  o.z = (v.z - mu)*rstd*g.z + bt.z + xr.z;
  o.w = (v.w - mu)*rstd*g.w + bt.w + xr.w;
  ((float4*)(xout + (size_t)row*DM))[t] = o;
  if (bout) {
    __hip_bfloat16* bp = bout + (size_t)row*DM + t*4;
    bp[0] = __float2bfloat16(o.x);
    bp[1] = __float2bfloat16(o.y);
    bp[2] = __float2bfloat16(o.z);
    bp[3] = __float2bfloat16(o.w);
  }
}

// ---------------------------------------------------------------------------
// Fused weight prep: all 6 transposes (fp32 [K][N] -> bf16 [N][K]) + x->bf16
// convert, one launch. Linear blockIdx decode; all dims compile-time.
// ---------------------------------------------------------------------------
__device__ __forceinline__ void tc_tile(
    const float* __restrict__ s, __hip_bfloat16* __restrict__ d,
    int K, int N, int bx, int by, int tx, int ty)
{
  __shared__ float tile[32][33];
  const int k0 = by * 32, n0 = bx * 32;
  for (int i = ty; i < 32; i += 8)
    tile[i][tx] = s[(size_t)(k0+i)*N + n0 + tx];
  __syncthreads();
  for (int i = ty; i < 32; i += 8)
    d[(size_t)(n0+i)*K + k0 + tx] = __float2bfloat16(tile[tx][i]);
}

__global__ __launch_bounds__(256) void prep(
    const float* __restrict__ x,    __hip_bfloat16* __restrict__ xb,
    const float* __restrict__ wq,   const float* __restrict__ wk,
    const float* __restrict__ wv,   __hip_bfloat16* __restrict__ wqkvT,
    const float* __restrict__ wo,   __hip_bfloat16* __restrict__ woT,
    const float* __restrict__ w_in, __hip_bfloat16* __restrict__ w_inT,
    const float* __restrict__ w_out,__hip_bfloat16* __restrict__ w_outT)
{
  const int bid = blockIdx.x;
  const int tx = threadIdx.x & 31, ty = threadIdx.x >> 5;
  if (bid < 3072) {                       // wq/wk/wv: per-head [DM][DH] -> [DH][DM]
    const int which = bid >> 10;          // 0=q 1=k 2=v
    const int i = bid & 1023;
    const int z = i >> 6;                 // head, 16
    const int rem = i & 63;               // 2 x 32
    const int bx = rem & 1, by = rem >> 1;
    const float* s = (which == 0 ? wq : which == 1 ? wk : wv) + (size_t)z*DM*DH;
    __hip_bfloat16* d = wqkvT + (size_t)which*1024*1024 + (size_t)z*DH*DM;
    tc_tile(s, d, DM, DH, bx, by, tx, ty);
  } else if (bid < 4096) {                // wo: [DM][DM] -> [DM][DM]
    const int i = bid - 3072;
    tc_tile(wo, woT, DM, DM, i & 31, i >> 5, tx, ty);
  } else if (bid < 8192) {                // w_in: [DM][DMLP] -> [DMLP][DM]
    const int i = bid - 4096;
    tc_tile(w_in, w_inT, DM, DMLP, i & 127, i >> 7, tx, ty);
  } else if (bid < 12288) {               // w_out: [DMLP][DM] -> [DM][DMLP]
    const int i = bid - 8192;
    tc_tile(w_out, w_outT, DMLP, DM, i & 31, i >> 5, tx, ty);
  } else {                                // x -> bf16
    const int i = (bid - 12288)*256 + (int)threadIdx.x;
    const float4 v = ((const float4*)x)[i];
    __hip_bfloat16* bp = xb + (size_t)i*4;
    bp[0] = __float2bfloat16(v.x);
    bp[1] = __float2bfloat16(v.y);
    bp[2] = __float2bfloat16(v.z);
    bp[3] = __float2bfloat16(v.w);
  }
}

extern "C" void kernel_launch(void* const* d_in, const int* in_sizes, int n_in,
                              void* d_out, int out_size, void* d_ws, size_t ws_size,
                              hipStream_t stream)
{
  const float* x     = (const float*)d_in[0];
  const float* wq    = (const float*)d_in[1];
  const float* wk    = (const float*)d_in[2];
  const float* wv    = (const float*)d_in[3];
  const float* wo    = (const float*)d_in[4];
  const float* w_in  = (const float*)d_in[5];
  const float* b_in  = (const float*)d_in[6];
  const float* w_out = (const float*)d_in[7];
  const float* b_out = (const float*)d_in[8];
  const float* g1    = (const float*)d_in[9];
  const float* bt1   = (const float*)d_in[10];
  const float* g2    = (const float*)d_in[11];
  const float* bt2   = (const float*)d_in[12];
  float* out = (float*)d_out;

  // Workspace map (MiB; base footprint 112 MiB).
  //   0-8 xb | 8-14 wqkvT | 14-16 woT | 16-24 w_inT | 24-32 w_outT
  //   32-56 qkvb + 56-64 vtb (dead after attn)
  //   64-72 attn_o (dead after proj)
  //   proj partials: P0 32-48, P1 48-64 (SPLIT=2 fallback)
  //   x1 72-88 | x1b 88-96 | hbuf 32-64 (over dead partials)
  //   mlp2 partials: M0 0-16, M1 96-112 (SPLIT=2 fallback)
  //   IF ws_size >= 176 MiB: proj AND mlp2 use SPLIT=4 with 4x16 MiB
  //   partials at 112..176 (region free at both times).
  char* ws = (char*)d_ws;
  __hip_bfloat16* xb     = (__hip_bfloat16*)(ws + 0);
  __hip_bfloat16* wqkvT  = (__hip_bfloat16*)(ws + 8388608);
  __hip_bfloat16* woT    = (__hip_bfloat16*)(ws + 14680064);
  __hip_bfloat16* w_inT  = (__hip_bfloat16*)(ws + 16777216);
  __hip_bfloat16* w_outT = (__hip_bfloat16*)(ws + 25165824);
  __hip_bfloat16* qkvb   = (__hip_bfloat16*)(ws + 33554432);
  __hip_bfloat16* vtb    = (__hip_bfloat16*)(ws + 58720256);
  __hip_bfloat16* attn_o = (__hip_bfloat16*)(ws + 67108864);
  float*          P0     = (float*)(ws + 33554432);    // 32 MiB (P1 = +16 MiB)
  float*          x1     = (float*)(ws + 75497472);    // 72 MiB
  __hip_bfloat16* x1b    = (__hip_bfloat16*)(ws + 92274688);  // 88 MiB
  __hip_bfloat16* hbuf   = (__hip_bfloat16*)(ws + 33554432);  // 32 MiB
  float*          M0     = (float*)(ws + 0);           // 0 MiB
  float*          M1     = (float*)(ws + 100663296);   // 96 MiB -> ends 112 MiB
  float*          P1     = (float*)(ws + 50331648);    // 48 MiB

  const long long PROJ_ZS = (long long)ROWS * DM;          // 16 MiB in floats
  const long long MLP_ZS  = 100663296LL / 4;               // M0 -> M1 offset in floats
  const bool big_ws = ws_size >= (size_t)176*1024*1024;
  float* Zb = (float*)(ws + (size_t)112*1024*1024);        // 4x16 MiB partials
  const long long ZS = (long long)ROWS * DM;

  // one fused prep launch: 6 transposes + x->bf16
  prep<<<16384, 256, 0, stream>>>(x, xb, wq, wk, wv, wqkvT, wo, woT,
                                  w_in, w_inT, w_out, w_outT);

  // QKV: grid (32, 24) = 768 blocks = 3 blocks/CU; V-section blocks write
  // straight to vtb (transpose fused into epilogue; transpose_v removed)
  gemm_bt<128,1,1,0,0,1><<<dim3(ROWS/128, 3072/128), 256, 0, stream>>>(
      xb, wqkvT, nullptr, qkvb, nullptr, ROWS, 3072, DM, 0, vtb);

  // attn: grid (bh=32, y=16, z=2) = 1024 blocks of 256 thr = 4 blocks/CU
  attn_kernel<<<dim3(BATCH*NH, 16, 2), 256, 0, stream>>>(qkvb, vtb, attn_o);

  // proj: SPLIT=4 when workspace allows (region 112..176 free here)
  if (big_ws) {
    gemm_bt<128,4,0,0,0,0><<<dim3(ROWS/128, DM/128, 4), 256, 0, stream>>>(
        attn_o, woT, Zb, nullptr, nullptr, ROWS, DM, DM, ZS, nullptr);
    ln_res<<<ROWS, 256, 0, stream>>>(Zb, Zb + ZS, Zb + 2*ZS, Zb + 3*ZS, nullptr, x, x1, x1b, g1, bt1);
  } else {
    gemm_bt<128,2,0,0,0,0><<<dim3(ROWS/128, DM/128, 2), 256, 0, stream>>>(
        attn_o, woT, P0, nullptr, nullptr, ROWS, DM, DM, PROJ_ZS, nullptr);
    ln_res<<<ROWS, 256, 0, stream>>>(P0, P1, nullptr, nullptr, nullptr, x, x1, x1b, g1, bt1);
  }

  // mlp1: gemm_bt<128> grid (32, 32) = 1024 blocks = 4 blocks/CU, bias+relu
  // (replaces gemm256's 256-block 1/CU grid; R0-proven configuration)
  gemm_bt<128,1,1,1,1,0><<<dim3(ROWS/128, DMLP/128), 256, 0, stream>>>(
      x1b, w_inT, nullptr, hbuf, b_in, ROWS, DMLP, DM, 0, nullptr);

  // mlp2: SPLIT=4 when workspace allows; else SPLIT=2 fallback
  if (big_ws) {
    gemm_bt<128,4,0,0,0,0><<<dim3(ROWS/128, DM/128, 4), 256, 0, stream>>>(
        hbuf, w_outT, Zb, nullptr, nullptr, ROWS, DM, DMLP, ZS, nullptr);
    ln_res<<<ROWS, 256, 0, stream>>>(Zb, Zb + ZS, Zb + 2*ZS, Zb + 3*ZS, b_out, x1, out, nullptr, g2, bt2);
  } else {
    gemm_bt<128,2,0,0,0,0><<<dim3(ROWS/128, DM/128, 2), 256, 0, stream>>>(
        hbuf, w_outT, M0, nullptr, nullptr, ROWS, DM, DMLP, MLP_ZS, nullptr);
    ln_res<<<ROWS, 256, 0, stream>>>(M0, M1, nullptr, nullptr, b_out, x1, out, nullptr, g2, bt2);
  }
}

// Round 10
// 334.709 us; speedup vs baseline: 1.0567x; 1.0567x over previous
//
#include <hip/hip_runtime.h>
#include <hip/hip_bf16.h>
#include <math.h>

#define DM 1024
#define SEQ 2048
#define DH 64
#define NH 16
#define DMLP 4096
#define BATCH 2
#define ROWS (BATCH*SEQ)   // 4096

typedef __attribute__((ext_vector_type(4))) float f32x4;
typedef __attribute__((ext_vector_type(8))) short bf16x8;

__device__ __forceinline__ void gl2lds16(const __hip_bfloat16* g, __hip_bfloat16* l) {
  __builtin_amdgcn_global_load_lds(
      (const __attribute__((address_space(1))) void*)g,
      (__attribute__((address_space(3))) void*)l, 16, 0, 0);
}

// ---------------------------------------------------------------------------
// 256x256-tile 2-phase bf16 GEMM -- mlp1 ONLY. grid (16,16) = 256 blocks =
// 1 block/CU fills the chip; measured 53.2 us / 663 TF. R9 tried mlp1 on
// gemm_bt<128> (32,32)=4 blocks/CU: 62.6 us / 549 TF -- at equal FLOP
// density the 256-tile's 16-MFMA-per-barrier x 8 waves wins; REVERTED.
// One __syncthreads per K-step, stage-next-then-compute. LDS XOR-swizzle
// both-sides. XCD: blockIdx.x = M-tile.
// ---------------------------------------------------------------------------
template<int BIAS, int RELU>
__global__ __launch_bounds__(512) void gemm256(
    const __hip_bfloat16* __restrict__ A,
    const __hip_bfloat16* __restrict__ BT,
    __hip_bfloat16* __restrict__ Cb,
    const float* __restrict__ bias,
    int M, int N, int K)
{
  __shared__ __align__(16) __hip_bfloat16 As[2][256*64];
  __shared__ __align__(16) __hip_bfloat16 Bs[2][256*64];
  const int t = threadIdx.x;
  const int wave = t >> 6, lane = t & 63;
  const int col = lane & 15, quad = lane >> 4;
  const int wm = wave >> 2, wn = wave & 3;
  const int m0 = blockIdx.x * 256, n0 = blockIdx.y * 256;

  const int srow = wave*16 + (lane >> 3);
  const int sg   = ((lane & 7) ^ (lane >> 3)) * 8;
  const __hip_bfloat16* gA = A  + (size_t)(m0 + srow)*K + sg;
  const __hip_bfloat16* gB = BT + (size_t)(n0 + srow)*K + sg;
  const size_t rK8 = (size_t)8*K, rK128 = (size_t)128*K;

  const int aoff = (wm*128 + col)*64;
  const int boff = (wn*64  + col)*64;
  const int sw0 = ( quad      ^ (col & 7))*8;   // k-chunk 0 (k=0..31)
  const int sw1 = ((quad + 4) ^ (col & 7))*8;   // k-chunk 1 (k=32..63)

  f32x4 acc[8][4] = {};
  const int NT = K >> 6;

#define STG_A(c, h, k0) do { \
    const __hip_bfloat16* s_ = gA + (size_t)(h)*rK128 + (k0); \
    __hip_bfloat16* d_ = &As[c][((h)*128 + wave*16)*64]; \
    gl2lds16(s_, d_); gl2lds16(s_ + rK8, d_ + 512); } while (0)
#define STG_B(c, h, k0) do { \
    const __hip_bfloat16* s_ = gB + (size_t)(h)*rK128 + (k0); \
    __hip_bfloat16* d_ = &Bs[c][((h)*128 + wave*16)*64]; \
    gl2lds16(s_, d_); gl2lds16(s_ + rK8, d_ + 512); } while (0)
#define STAGE(c, k0) do { \
    STG_A(c, 0, k0); STG_A(c, 1, k0); \
    STG_B(c, 0, k0); STG_B(c, 1, k0); } while (0)

  STAGE(0, 0);
  for (int ks = 0; ks < NT; ks++) {
    const int cur = ks & 1;
    __syncthreads();                    // drains vmcnt(0): buf[cur] ready
    if (ks + 1 < NT) STAGE(cur ^ 1, (ks + 1) << 6);  // in flight during compute
    const __hip_bfloat16* Ab = As[cur];
    const __hip_bfloat16* Bb = Bs[cur];
    bf16x8 af[8], bf[4];
    // k-chunk 0
    #pragma unroll
    for (int i = 0; i < 8; i++) af[i] = *(const bf16x8*)&Ab[aoff + i*1024 + sw0];
    #pragma unroll
    for (int j = 0; j < 4; j++) bf[j] = *(const bf16x8*)&Bb[boff + j*1024 + sw0];
    #pragma unroll
    for (int i = 0; i < 8; i++)
      #pragma unroll
      for (int j = 0; j < 4; j++)
        acc[i][j] = __builtin_amdgcn_mfma_f32_16x16x32_bf16(af[i], bf[j], acc[i][j], 0, 0, 0);
    // k-chunk 1
    #pragma unroll
    for (int i = 0; i < 8; i++) af[i] = *(const bf16x8*)&Ab[aoff + i*1024 + sw1];
    #pragma unroll
    for (int j = 0; j < 4; j++) bf[j] = *(const bf16x8*)&Bb[boff + j*1024 + sw1];
    #pragma unroll
    for (int i = 0; i < 8; i++)
      #pragma unroll
      for (int j = 0; j < 4; j++)
        acc[i][j] = __builtin_amdgcn_mfma_f32_16x16x32_bf16(af[i], bf[j], acc[i][j], 0, 0, 0);
  }
#undef STAGE
#undef STG_A
#undef STG_B

  #pragma unroll
  for (int i = 0; i < 8; i++) {
    const int gm = m0 + wm*128 + i*16 + quad*4;
    #pragma unroll
    for (int j = 0; j < 4; j++) {
      const int gn = n0 + wn*64 + j*16 + col;
      float bv = 0.f;
      if (BIAS) bv = bias[gn];
      #pragma unroll
      for (int r = 0; r < 4; r++) {
        float v = acc[i][j][r];          // C/D: col=lane&15, row=quad*4+reg
        if (BIAS) v += bv;
        if (RELU) v = fmaxf(v, 0.f);
        Cb[(size_t)(gm + r)*N + gn] = __float2bfloat16(v);
      }
    }
  }
}

// ---------------------------------------------------------------------------
// bf16 GEMM: C[M,N] = A[M,K] * BT[N,K]^T.  TM x 128 tile, 256 thr, 16x16x32
// MFMA, double-buffered global_load_lds staging. QKV (SPLIT=1, bf16 out,
// grid 32x24 = 3 blocks/CU) and proj/mlp2 (split-K, fp32 partials).
// QKV=1: N-blocks with n0 >= 2048 (the V section) write DIRECTLY to
// vt[(bh*64+e)*SEQ + s] (8B short4: 4 consecutive s) -- fused transpose_v.
// Split-K policy (R10): proj SPLIT=2 (SPLIT=4's gemm gain at Ks=256 was
// smaller than ln1's +64 MiB partial traffic); mlp2 SPLIT=4 (gemm gain
// 56.6->50.2 exceeds ln2's extra ~5 us). XCD: blockIdx.x = M.
// ---------------------------------------------------------------------------
template<int TM, int SPLIT, int OUT_BF16, int BIAS, int RELU, int QKV>
__global__ __launch_bounds__(256) void gemm_bt(
    const __hip_bfloat16* __restrict__ A,
    const __hip_bfloat16* __restrict__ BT,
    float* __restrict__ Cf,
    __hip_bfloat16* __restrict__ Cb,
    const float* __restrict__ bias,
    int M, int N, int K, long long zstride,
    __hip_bfloat16* __restrict__ vtout)
{
  constexpr int ASZ = TM*32;
  constexpr int MI  = (TM == 128) ? 4 : 2;
  __shared__ __align__(16) __hip_bfloat16 As[2*ASZ];
  __shared__ __align__(16) __hip_bfloat16 Bs[2*4096];
  const int t    = threadIdx.x;
  const int wave = t >> 6;
  const int lane = t & 63;
  const int col  = lane & 15;
  const int quad = lane >> 4;
  const int m0 = blockIdx.x * TM;     // M on x: XCD-local A reuse
  const int n0 = blockIdx.y * 128;
  const int wm = (wave >> 1) * (TM/2);
  const int wn = (wave & 1) * 64;

  const int Ks = K / SPLIT;
  const int kz = (SPLIT > 1) ? (int)blockIdx.z * Ks : 0;

  const int srow = t >> 2;
  const int scw  = ((t & 3) ^ ((srow >> 1) & 3)) * 8;
  const __hip_bfloat16* gA = A  + (size_t)(m0 + srow) * K + kz + scw;
  const __hip_bfloat16* gB = BT + (size_t)(n0 + srow) * K + kz + scw;
  const size_t rstep = (size_t)64 * K;

  const int scr = (quad ^ ((col >> 1) & 3)) * 8;

  f32x4 acc[MI][4] = {};

#define ISSUE(k0, buf) do {                                            \
    __hip_bfloat16* la = As + (buf)*ASZ  + wave*512;                   \
    __hip_bfloat16* lb = Bs + (buf)*4096 + wave*512;                   \
    gl2lds16(gA + (k0), la);                                           \
    if (TM == 128) gl2lds16(gA + rstep + (k0), la + 2048);             \
    gl2lds16(gB + (k0), lb);                                           \
    gl2lds16(gB + rstep + (k0), lb + 2048);                            \
  } while (0)

  ISSUE(0, 0);
  for (int k0 = 0; k0 < Ks; k0 += 32) {
    const int cur = (k0 >> 5) & 1;
    __syncthreads();                 // drains vmcnt(0): cur buffer ready
    if (k0 + 32 < Ks) ISSUE(k0 + 32, cur ^ 1);   // in flight during compute
    const __hip_bfloat16* Ab = As + cur*ASZ;
    const __hip_bfloat16* Bb = Bs + cur*4096;
    bf16x8 af[MI], bf[4];
    #pragma unroll
    for (int i = 0; i < MI; i++)
      af[i] = *(const bf16x8*)&Ab[(wm + i*16 + col)*32 + scr];
    #pragma unroll
    for (int j = 0; j < 4; j++)
      bf[j] = *(const bf16x8*)&Bb[(wn + j*16 + col)*32 + scr];
    #pragma unroll
    for (int i = 0; i < MI; i++)
      #pragma unroll
      for (int j = 0; j < 4; j++)
        acc[i][j] = __builtin_amdgcn_mfma_f32_16x16x32_bf16(af[i], bf[j], acc[i][j], 0, 0, 0);
  }
#undef ISSUE

  float* Cfz = (SPLIT > 1) ? (Cf + (size_t)blockIdx.z * zstride) : Cf;

  if (QKV && n0 >= 2048) {
    // V section: write transposed to vt[(bh*64+e)*SEQ + s].
    #pragma unroll
    for (int i = 0; i < MI; i++) {
      const int cm0 = m0 + wm + i*16 + quad*4;   // row of C (r adds 0..3)
      const int bb  = cm0 >> 11;                 // batch (SEQ=2048)
      const int s   = cm0 & 2047;                // seq pos (mult of 4)
      #pragma unroll
      for (int j = 0; j < 4; j++) {
        const int cn2 = n0 + wn + j*16 + col - 2048;  // 0..1023
        const int hh = cn2 >> 6, e = cn2 & 63;
        __hip_bfloat16 tmp[4];
        #pragma unroll
        for (int r = 0; r < 4; r++) tmp[r] = __float2bfloat16(acc[i][j][r]);
        *(short4*)&vtout[((size_t)(bb*16 + hh)*64 + e)*SEQ + s] = *(const short4*)tmp;
      }
    }
    return;
  }

  #pragma unroll
  for (int i = 0; i < MI; i++) {
    #pragma unroll
    for (int j = 0; j < 4; j++) {
      const int cn = n0 + wn + j*16 + col;
      float bv = 0.f;
      if (BIAS) bv = bias[cn];
      #pragma unroll
      for (int r = 0; r < 4; r++) {
        const int cm = m0 + wm + i*16 + quad*4 + r;   // C/D: col=lane&15, row=quad*4+reg
        float v = acc[i][j][r];
        if (BIAS) v += bv;
        if (RELU) v = fmaxf(v, 0.f);
        if (OUT_BF16) Cb[(size_t)cm * N + cn] = __float2bfloat16(v);
        else          Cfz[(size_t)cm * N + cn] = v;
      }
    }
  }
}

// ---------------------------------------------------------------------------
// Flash attention (R6/R8 proven version). R7 post-mortem: attn needs ~16
// waves/CU to hide LDS/global latency; 2-wave blocks collapsed all pipes.
// Grid (bh=32, y=16, z=2) = 1024 blocks of 256 thr = 4 blocks/CU (LDS 40KiB).
// Q in registers; K/V double-buffered global_load_lds w/ XOR swizzle;
// no-max softmax, deferred l-reduction.
// ---------------------------------------------------------------------------
__global__ __launch_bounds__(256) void attn_kernel(
    const __hip_bfloat16* __restrict__ qkv,
    const __hip_bfloat16* __restrict__ vt,
    __hip_bfloat16* __restrict__ aout)
{
  __shared__ __align__(16) __hip_bfloat16 Ks[2][64*64];
  __shared__ __align__(16) __hip_bfloat16 Vts[2][64*64];
  __shared__ __align__(16) __hip_bfloat16 Ps[4][16*64];

  const int bh = blockIdx.x, b = bh >> 4, h = bh & 15;
  const int t = threadIdx.x, wave = t >> 6, lane = t & 63;
  const int col = lane & 15, quad = lane >> 4;
  const float SC = 0.125f * 1.44269504f;   // 1/sqrt(dh) * log2(e)

  const int r0  = t >> 3;                 // row within 32-row half
  const int cs0 = (t & 7) ^ (r0 & 7);     // XOR-swizzled source chunk
  const __hip_bfloat16* kbase = qkv + (size_t)b*SEQ*3072 + 1024 + h*64;
  const __hip_bfloat16* vbase = vt + (size_t)bh*64*SEQ;

#define AISSUE(j0, buf) do {                                                      \
    gl2lds16(kbase + (size_t)((j0) + r0)*3072      + cs0*8, &Ks[buf][wave*512]);  \
    gl2lds16(kbase + (size_t)((j0) + 32 + r0)*3072 + cs0*8, &Ks[buf][2048 + wave*512]); \
    gl2lds16(vbase + (size_t)r0*SEQ        + (j0) + cs0*8,  &Vts[buf][wave*512]); \
    gl2lds16(vbase + (size_t)(32 + r0)*SEQ + (j0) + cs0*8,  &Vts[buf][2048 + wave*512]); \
  } while (0)

  const int tile = blockIdx.z ? (31 - (int)blockIdx.y) : (int)blockIdx.y;
  const int i0 = tile * 64;
  const int i0w = i0 + wave*16;

  bf16x8 aq[2];
  #pragma unroll
  for (int kk = 0; kk < 2; kk++)
    aq[kk] = *(const bf16x8*)&qkv[((size_t)(b*SEQ + i0w + col))*3072 + h*64 + kk*32 + quad*8];

  f32x4 O[4] = {};
  float lsum[4] = {0.f, 0.f, 0.f, 0.f};

  const int njt = tile + 1;
  AISSUE(0, 0);
  for (int jt = 0; jt < njt; jt++) {
    const int cur = jt & 1;
    const int j0 = jt * 64;
    __syncthreads();        // drains vmcnt(0): cur buffers ready
    if (jt + 1 < njt) AISSUE(j0 + 64, cur ^ 1);

    f32x4 S[4] = {};
    #pragma unroll
    for (int kk = 0; kk < 2; kk++) {
      const int sl = ((kk*4 + quad) ^ (col & 7)) * 8;
      #pragma unroll
      for (int jl = 0; jl < 4; jl++) {
        bf16x8 bk = *(const bf16x8*)&Ks[cur][(jl*16 + col)*64 + sl];
        S[jl] = __builtin_amdgcn_mfma_f32_16x16x32_bf16(aq[kk], bk, S[jl], 0, 0, 0);
      }
    }

    const bool diag = (jt == tile);
    #pragma unroll
    for (int r = 0; r < 4; r++) {
      const int row = quad*4 + r;
      const int ig = i0 + wave*16 + row;
      #pragma unroll
      for (int jl = 0; jl < 4; jl++) {
        float p = exp2f(S[jl][r] * SC);
        if (diag && (j0 + jl*16 + col > ig)) p = 0.f;
        lsum[r] += p;
        const int c = jl*2 + (col >> 3);
        Ps[wave][row*64 + (c ^ (row & 7))*8 + (col & 7)] = __float2bfloat16(p);
      }
    }

    #pragma unroll
    for (int kk = 0; kk < 2; kk++) {
      const int sl = ((kk*4 + quad) ^ (col & 7)) * 8;
      bf16x8 ap = *(const bf16x8*)&Ps[wave][col*64 + sl];
      #pragma unroll
      for (int et = 0; et < 4; et++) {
        bf16x8 bv = *(const bf16x8*)&Vts[cur][(et*16 + col)*64 + sl];
        O[et] = __builtin_amdgcn_mfma_f32_16x16x32_bf16(ap, bv, O[et], 0, 0, 0);
      }
    }
  }

  #pragma unroll
  for (int r = 0; r < 4; r++) {
    float s = lsum[r];
    s += __shfl_xor(s, 1);
    s += __shfl_xor(s, 2);
    s += __shfl_xor(s, 4);
    s += __shfl_xor(s, 8);
    const float inv = 1.f / s;
    const int m = b*SEQ + i0w + quad*4 + r;
    #pragma unroll
    for (int et = 0; et < 4; et++)
      aout[(size_t)m*DM + h*64 + et*16 + col] = __float2bfloat16(O[et][r] * inv);
  }
#undef AISSUE
}

// ---------------------------------------------------------------------------
// LayerNorm(y0 [+ y1 + y2 + y3] [+ bias])*g + b + residual -> fp32 out
// (+ opt bf16 copy).  y1..y3 nullable (split-K partial sums).
// ---------------------------------------------------------------------------
__global__ __launch_bounds__(256) void ln_res(
    const float* __restrict__ y0,
    const float* __restrict__ y1,
    const float* __restrict__ y2,
    const float* __restrict__ y3,
    const float* __restrict__ bias,
    const float* __restrict__ xres,
    float* __restrict__ xout,
    __hip_bfloat16* __restrict__ bout,
    const float* __restrict__ gamma,
    const float* __restrict__ beta)
{
  const int row = blockIdx.x;
  const int t = threadIdx.x;
  float4 v = ((const float4*)(y0 + (size_t)row*DM))[t];
  if (y1) {
    const float4 w = ((const float4*)(y1 + (size_t)row*DM))[t];
    v.x += w.x; v.y += w.y; v.z += w.z; v.w += w.w;
  }
  if (y2) {
    const float4 w = ((const float4*)(y2 + (size_t)row*DM))[t];
    v.x += w.x; v.y += w.y; v.z += w.z; v.w += w.w;
  }
  if (y3) {
    const float4 w = ((const float4*)(y3 + (size_t)row*DM))[t];
    v.x += w.x; v.y += w.y; v.z += w.z; v.w += w.w;
  }
  if (bias) {
    const float4 w = ((const float4*)bias)[t];
    v.x += w.x; v.y += w.y; v.z += w.z; v.w += w.w;
  }
  float s  = v.x + v.y + v.z + v.w;
  float sq = v.x*v.x + v.y*v.y + v.z*v.z + v.w*v.w;
  #pragma unroll
  for (int off = 32; off > 0; off >>= 1) {
    s  += __shfl_down(s, off);
    sq += __shfl_down(sq, off);
  }
  __shared__ float red[8];
  const int wave = t >> 6, lane = t & 63;
  if (lane == 0) { red[wave] = s; red[4 + wave] = sq; }
  __syncthreads();
  s  = red[0] + red[1] + red[2] + red[3];
  sq = red[4] + red[5] + red[6] + red[7];
  const float mu   = s * (1.f/DM);
  const float var  = sq * (1.f/DM) - mu*mu;
  const float rstd = rsqrtf(var + 1e-5f);
  const float4 g  = ((const float4*)gamma)[t];
  const float4 bt = ((const float4*)beta)[t];
  const float4 xr = ((const float4*)(xres + (size_t)row*DM))[t];
  float4 o;
  o.x = (v.x - mu)*rstd*g.x + bt.x + xr.x;
  o.y = (v.y - mu)*rstd*g.y + bt.y + xr.y;
  o.z = (v.z - mu)*rstd*g.z + bt.z + xr.z;
  o.w = (v.w - mu)*rstd*g.w + bt.w + xr.w;
  ((float4*)(xout + (size_t)row*DM))[t] = o;
  if (bout) {
    __hip_bfloat16* bp = bout + (size_t)row*DM + t*4;
    bp[0] = __float2bfloat16(o.x);
    bp[1] = __float2bfloat16(o.y);
    bp[2] = __float2bfloat16(o.z);
    bp[3] = __float2bfloat16(o.w);
  }
}

// ---------------------------------------------------------------------------
// Fused weight prep: all 6 transposes (fp32 [K][N] -> bf16 [N][K]) + x->bf16
// convert, one launch. Linear blockIdx decode; all dims compile-time.
// ---------------------------------------------------------------------------
__device__ __forceinline__ void tc_tile(
    const float* __restrict__ s, __hip_bfloat16* __restrict__ d,
    int K, int N, int bx, int by, int tx, int ty)
{
  __shared__ float tile[32][33];
  const int k0 = by * 32, n0 = bx * 32;
  for (int i = ty; i < 32; i += 8)
    tile[i][tx] = s[(size_t)(k0+i)*N + n0 + tx];
  __syncthreads();
  for (int i = ty; i < 32; i += 8)
    d[(size_t)(n0+i)*K + k0 + tx] = __float2bfloat16(tile[tx][i]);
}

__global__ __launch_bounds__(256) void prep(
    const float* __restrict__ x,    __hip_bfloat16* __restrict__ xb,
    const float* __restrict__ wq,   const float* __restrict__ wk,
    const float* __restrict__ wv,   __hip_bfloat16* __restrict__ wqkvT,
    const float* __restrict__ wo,   __hip_bfloat16* __restrict__ woT,
    const float* __restrict__ w_in, __hip_bfloat16* __restrict__ w_inT,
    const float* __restrict__ w_out,__hip_bfloat16* __restrict__ w_outT)
{
  const int bid = blockIdx.x;
  const int tx = threadIdx.x & 31, ty = threadIdx.x >> 5;
  if (bid < 3072) {                       // wq/wk/wv: per-head [DM][DH] -> [DH][DM]
    const int which = bid >> 10;          // 0=q 1=k 2=v
    const int i = bid & 1023;
    const int z = i >> 6;                 // head, 16
    const int rem = i & 63;               // 2 x 32
    const int bx = rem & 1, by = rem >> 1;
    const float* s = (which == 0 ? wq : which == 1 ? wk : wv) + (size_t)z*DM*DH;
    __hip_bfloat16* d = wqkvT + (size_t)which*1024*1024 + (size_t)z*DH*DM;
    tc_tile(s, d, DM, DH, bx, by, tx, ty);
  } else if (bid < 4096) {                // wo: [DM][DM] -> [DM][DM]
    const int i = bid - 3072;
    tc_tile(wo, woT, DM, DM, i & 31, i >> 5, tx, ty);
  } else if (bid < 8192) {                // w_in: [DM][DMLP] -> [DMLP][DM]
    const int i = bid - 4096;
    tc_tile(w_in, w_inT, DM, DMLP, i & 127, i >> 7, tx, ty);
  } else if (bid < 12288) {               // w_out: [DMLP][DM] -> [DM][DMLP]
    const int i = bid - 8192;
    tc_tile(w_out, w_outT, DMLP, DM, i & 31, i >> 5, tx, ty);
  } else {                                // x -> bf16
    const int i = (bid - 12288)*256 + (int)threadIdx.x;
    const float4 v = ((const float4*)x)[i];
    __hip_bfloat16* bp = xb + (size_t)i*4;
    bp[0] = __float2bfloat16(v.x);
    bp[1] = __float2bfloat16(v.y);
    bp[2] = __float2bfloat16(v.z);
    bp[3] = __float2bfloat16(v.w);
  }
}

extern "C" void kernel_launch(void* const* d_in, const int* in_sizes, int n_in,
                              void* d_out, int out_size, void* d_ws, size_t ws_size,
                              hipStream_t stream)
{
  const float* x     = (const float*)d_in[0];
  const float* wq    = (const float*)d_in[1];
  const float* wk    = (const float*)d_in[2];
  const float* wv    = (const float*)d_in[3];
  const float* wo    = (const float*)d_in[4];
  const float* w_in  = (const float*)d_in[5];
  const float* b_in  = (const float*)d_in[6];
  const float* w_out = (const float*)d_in[7];
  const float* b_out = (const float*)d_in[8];
  const float* g1    = (const float*)d_in[9];
  const float* bt1   = (const float*)d_in[10];
  const float* g2    = (const float*)d_in[11];
  const float* bt2   = (const float*)d_in[12];
  float* out = (float*)d_out;

  // Workspace map (MiB; base footprint 112 MiB).
  //   0-8 xb | 8-14 wqkvT | 14-16 woT | 16-24 w_inT | 24-32 w_outT
  //   32-56 qkvb + 56-64 vtb (dead after attn)
  //   64-72 attn_o (dead after proj)
  //   proj partials: P0 32-48, P1 48-64 (SPLIT=2)
  //   x1 72-88 | x1b 88-96 | hbuf 32-64 (over dead partials)
  //   mlp2 partials: M0 0-16, M1 96-112 (SPLIT=2 fallback)
  //   IF ws_size >= 176 MiB: mlp2 SPLIT=4, 4x16 MiB partials at 112..176.
  char* ws = (char*)d_ws;
  __hip_bfloat16* xb     = (__hip_bfloat16*)(ws + 0);
  __hip_bfloat16* wqkvT  = (__hip_bfloat16*)(ws + 8388608);
  __hip_bfloat16* woT    = (__hip_bfloat16*)(ws + 14680064);
  __hip_bfloat16* w_inT  = (__hip_bfloat16*)(ws + 16777216);
  __hip_bfloat16* w_outT = (__hip_bfloat16*)(ws + 25165824);
  __hip_bfloat16* qkvb   = (__hip_bfloat16*)(ws + 33554432);
  __hip_bfloat16* vtb    = (__hip_bfloat16*)(ws + 58720256);
  __hip_bfloat16* attn_o = (__hip_bfloat16*)(ws + 67108864);
  float*          P0     = (float*)(ws + 33554432);    // 32 MiB (P1 = +16 MiB)
  float*          x1     = (float*)(ws + 75497472);    // 72 MiB
  __hip_bfloat16* x1b    = (__hip_bfloat16*)(ws + 92274688);  // 88 MiB
  __hip_bfloat16* hbuf   = (__hip_bfloat16*)(ws + 33554432);  // 32 MiB
  float*          M0     = (float*)(ws + 0);           // 0 MiB
  float*          M1     = (float*)(ws + 100663296);   // 96 MiB -> ends 112 MiB
  float*          P1     = (float*)(ws + 50331648);    // 48 MiB

  const long long PROJ_ZS = (long long)ROWS * DM;          // 16 MiB in floats
  const long long MLP_ZS  = 100663296LL / 4;               // M0 -> M1 offset in floats
  const bool big_ws = ws_size >= (size_t)176*1024*1024;
  float* Zb = (float*)(ws + (size_t)112*1024*1024);        // 4x16 MiB partials
  const long long ZS = (long long)ROWS * DM;

  // one fused prep launch: 6 transposes + x->bf16
  prep<<<16384, 256, 0, stream>>>(x, xb, wq, wk, wv, wqkvT, wo, woT,
                                  w_in, w_inT, w_out, w_outT);

  // QKV: grid (32, 24) = 768 blocks = 3 blocks/CU; V-section blocks write
  // straight to vtb (transpose fused into epilogue)
  gemm_bt<128,1,1,0,0,1><<<dim3(ROWS/128, 3072/128), 256, 0, stream>>>(
      xb, wqkvT, nullptr, qkvb, nullptr, ROWS, 3072, DM, 0, vtb);

  // attn: grid (bh=32, y=16, z=2) = 1024 blocks of 256 thr = 4 blocks/CU
  attn_kernel<<<dim3(BATCH*NH, 16, 2), 256, 0, stream>>>(qkvb, vtb, attn_o);

  // proj: SPLIT=2 (R10: SPLIT=4's gemm gain at Ks=256 < ln1's +64 MiB
  // partial-read traffic; 2 partials is the sweet spot here)
  gemm_bt<128,2,0,0,0,0><<<dim3(ROWS/128, DM/128, 2), 256, 0, stream>>>(
      attn_o, woT, P0, nullptr, nullptr, ROWS, DM, DM, PROJ_ZS, nullptr);
  ln_res<<<ROWS, 256, 0, stream>>>(P0, P1, nullptr, nullptr, nullptr, x, x1, x1b, g1, bt1);

  // mlp1: 256x256 2-phase kernel, grid (16,16) = 256 blocks (REVERTED from
  // R9's gemm_bt<128>(32,32): 62.6 us vs gemm256's 53.2)
  gemm256<1,1><<<dim3(ROWS/256, DMLP/256), 512, 0, stream>>>(x1b, w_inT, hbuf, b_in, ROWS, DMLP, DM);

  // mlp2: SPLIT=4 when workspace allows; else SPLIT=2 fallback
  if (big_ws) {
    gemm_bt<128,4,0,0,0,0><<<dim3(ROWS/128, DM/128, 4), 256, 0, stream>>>(
        hbuf, w_outT, Zb, nullptr, nullptr, ROWS, DM, DMLP, ZS, nullptr);
    ln_res<<<ROWS, 256, 0, stream>>>(Zb, Zb + ZS, Zb + 2*ZS, Zb + 3*ZS, b_out, x1, out, nullptr, g2, bt2);
  } else {
    gemm_bt<128,2,0,0,0,0><<<dim3(ROWS/128, DM/128, 2), 256, 0, stream>>>(
        hbuf, w_outT, M0, nullptr, nullptr, ROWS, DM, DMLP, MLP_ZS, nullptr);
    ln_res<<<ROWS, 256, 0, stream>>>(M0, M1, nullptr, nullptr, b_out, x1, out, nullptr, g2, bt2);
  }
}